// Round 16
// baseline (286.180 us; speedup 1.0000x reference)
//
#include <hip/hip_runtime.h>
#include <hip/hip_bf16.h>

#define NN 50000
#define EE 500000
#define GG 8
#define INDIM 128
#define HID 64
#define NH 2
#define PB 32          // slice-blocks per graph in pooling stages
#define TM 32          // nodes per fc block (R11 proven; TM64 regressed R12)
#define KC 32          // k-chunk staged in LDS
#define CAP 64         // edge bucket capacity per node (max observed deg ~30)

// bf16 helpers (manual RTNE pack / bit-shift unpack)
__device__ inline unsigned short f2bf(float f) {
    unsigned int u = __float_as_uint(f);
    unsigned int r = (u + 0x7FFFu + ((u >> 16) & 1u)) >> 16;
    return (unsigned short)r;
}
__device__ inline unsigned int pack_bf16x2(float lo, float hi) {
    return (unsigned int)f2bf(lo) | ((unsigned int)f2bf(hi) << 16);
}
// order-preserving float<->uint encoding for atomicMax (0 < enc(any float))
__device__ inline unsigned int encf(float f) {
    unsigned int u = __float_as_uint(f);
    return (u & 0x80000000u) ? ~u : (u | 0x80000000u);
}
__device__ inline float decf(unsigned int e) {
    unsigned int u = (e & 0x80000000u) ? (e & 0x7FFFFFFFu) : ~e;
    return __uint_as_float(u);
}
__device__ inline int lower_bound_g(const int* __restrict__ gids, int target, int N) {
    int lo = 0, hi = N;
    while (lo < hi) { int mid = (lo + hi) >> 1; if (gids[mid] < target) lo = mid + 1; else hi = mid; }
    return lo;
}

// ---------------------------------------------------------------------------
// Bucket scatter (standalone: no LDS, low VGPR -> full occupancy for the
// latency-bound atomic/store storm. Fusing it with fc1 trapped it at the fc
// kernel's 21KB-LDS occupancy and cost ~25 us — R15 lesson.)
// ---------------------------------------------------------------------------
__global__ void scatter_kernel(const int* __restrict__ src, const int* __restrict__ dst,
                               int* __restrict__ cnt, unsigned short* __restrict__ esrc,
                               int E) {
    int e = blockIdx.x * blockDim.x + threadIdx.x;
    if (e < E) {
        int d = dst[e];
        int pos = atomicAdd(&cnt[d], 1);
        if (pos < CAP) esrc[(size_t)d * CAP + pos] = (unsigned short)src[e];
    }
}

// ---------------------------------------------------------------------------
// Register-tiled fc + attention dots (R11 TM=32 form): 256 threads ->
// 32 nodes x 128 cols, 4x4/thread. feat packed bf16x2; el/er fp32.
// ---------------------------------------------------------------------------
__global__ __launch_bounds__(256) void fc_attn_kernel(
        const float* __restrict__ X, const float* __restrict__ W,
        const float* __restrict__ al, const float* __restrict__ ar,
        unsigned int* __restrict__ featb, float* __restrict__ el,
        float* __restrict__ er, int K, int N) {
    int t = threadIdx.x;
    int tx = t & 31, ty = t >> 5;
    int n0 = blockIdx.x * TM;
    __shared__ float xT[KC][TM + 4];
    __shared__ float Wsh[KC][128];
    float acc[4][4] = {{0.f}};

    for (int kc = 0; kc < K; kc += KC) {
        {
            int r = t >> 3;
            int c4 = (t & 7) * 4;
            int n = n0 + r;
            float4 v = make_float4(0.f, 0.f, 0.f, 0.f);
            if (n < N) v = *(const float4*)&X[(size_t)n * K + kc + c4];
            xT[c4 + 0][r] = v.x;
            xT[c4 + 1][r] = v.y;
            xT[c4 + 2][r] = v.z;
            xT[c4 + 3][r] = v.w;
        }
        {
            const float4* Wg = (const float4*)&W[(size_t)kc * 128];
            float4* Ws4 = (float4*)&Wsh[0][0];
#pragma unroll
            for (int i = 0; i < 4; i++) Ws4[t + 256 * i] = Wg[t + 256 * i];
        }
        __syncthreads();
#pragma unroll
        for (int k = 0; k < KC; k++) {
            float4 xv = *(float4*)&xT[k][ty * 4];
            float4 wv = *(float4*)&Wsh[k][tx * 4];
            float xs[4] = {xv.x, xv.y, xv.z, xv.w};
            float wsv[4] = {wv.x, wv.y, wv.z, wv.w};
#pragma unroll
            for (int i = 0; i < 4; i++)
#pragma unroll
                for (int j = 0; j < 4; j++) acc[i][j] += xs[i] * wsv[j];
        }
        __syncthreads();
    }

    int head = tx >> 4;
    float alv[4], arv[4];
#pragma unroll
    for (int j = 0; j < 4; j++) {
        alv[j] = al[tx * 4 + j];
        arv[j] = ar[tx * 4 + j];
    }
#pragma unroll
    for (int i = 0; i < 4; i++) {
        int r = n0 + ty * 4 + i;
        if (r < N) {
            uint2 pk;
            pk.x = pack_bf16x2(acc[i][0], acc[i][1]);
            pk.y = pack_bf16x2(acc[i][2], acc[i][3]);
            *(uint2*)&featb[(size_t)r * 64 + tx * 2] = pk;
            float pl = 0.f, pr = 0.f;
#pragma unroll
            for (int j = 0; j < 4; j++) {
                pl += acc[i][j] * alv[j];
                pr += acc[i][j] * arv[j];
            }
            for (int off = 8; off; off >>= 1) {
                pl += __shfl_xor(pl, off, 64);
                pr += __shfl_xor(pr, off, 64);
            }
            if ((tx & 15) == 0) {
                el[r * 2 + head] = pl;
                er[r * 2 + head] = pr;
            }
        }
    }
}

// ---------------------------------------------------------------------------
// GAT edge softmax + aggregation + relu + head-mean: ONE WAVE PER NODE,
// FOUR EDGES PER ITERATION (R11 inline-shuffle gather — proven optimal).
// Edge-softmax without max subtraction (identical math, scores O(+-12)).
// ---------------------------------------------------------------------------
__global__ void gat_agg_kernel(const unsigned int* __restrict__ featb,
                               const float* __restrict__ el,
                               const float* __restrict__ er, const int* __restrict__ cnt,
                               const unsigned short* __restrict__ esrc,
                               float* __restrict__ hout,
                               const float* __restrict__ wg, const float* __restrict__ bg,
                               float* __restrict__ gatev, int doGate) {
    int wid = threadIdx.x >> 6;
    int lane = threadIdx.x & 63;
    int n = blockIdx.x * 4 + wid;
    if (n >= NN) return;
    int deg = cnt[n];
    deg = deg > CAP ? CAP : deg;
    int q = lane >> 4;     // which edge of a quad
    int l4 = lane & 15;    // covers uints 4*l4..4*l4+3 = cols 8*l4..8*l4+7
    float a8[8];
#pragma unroll
    for (int i = 0; i < 8; i++) a8[i] = 0.f;

    if (deg > 0) {
        float2 erv = ((const float2*)er)[n];
        bool v = lane < deg;
        int s = (int)esrc[(size_t)n * CAP + (v ? lane : 0)];
        float2 elv = ((const float2*)el)[s];
        float e0 = elv.x + erv.x; e0 = e0 > 0.f ? e0 : 0.2f * e0;
        float e1 = elv.y + erv.y; e1 = e1 > 0.f ? e1 : 0.2f * e1;
        float x0 = v ? __expf(e0) : 0.f;
        float x1 = v ? __expf(e1) : 0.f;
        float d0 = x0, d1 = x1;
        for (int off = 32; off; off >>= 1) {
            d0 += __shfl_xor(d0, off, 64);
            d1 += __shfl_xor(d1, off, 64);
        }
        float a0 = x0 / d0, a1 = x1 / d1;
        int headHi = (l4 >= 8);
        for (int e = 0; e < deg; e += 4) {
            int myE = e + q;
            bool ve = myE < deg;
            int pick = ve ? myE : e;
            int se = __shfl(s, pick, 64);
            float av0 = __shfl(a0, pick, 64);
            float av1 = __shfl(a1, pick, 64);
            float a = headHi ? av1 : av0;
            if (!ve) a = 0.f;
            uint4 fv = *(const uint4*)&featb[(size_t)se * 64 + l4 * 4];
            a8[0] += a * __uint_as_float(fv.x << 16);
            a8[1] += a * __uint_as_float(fv.x & 0xFFFF0000u);
            a8[2] += a * __uint_as_float(fv.y << 16);
            a8[3] += a * __uint_as_float(fv.y & 0xFFFF0000u);
            a8[4] += a * __uint_as_float(fv.z << 16);
            a8[5] += a * __uint_as_float(fv.z & 0xFFFF0000u);
            a8[6] += a * __uint_as_float(fv.w << 16);
            a8[7] += a * __uint_as_float(fv.w & 0xFFFF0000u);
        }
    }

    // combine quads (same cols, disjoint edge subsets), then relu
#pragma unroll
    for (int i = 0; i < 8; i++) {
        a8[i] += __shfl_xor(a8[i], 16, 64);
        a8[i] += __shfl_xor(a8[i], 32, 64);
        a8[i] = fmaxf(a8[i], 0.f);
    }
    // head mean: lane l4 pairs with l4^8 (head0 cols 8*l4.. <-> head1 same offset)
    float m8[8];
#pragma unroll
    for (int i = 0; i < 8; i++) m8[i] = 0.5f * (a8[i] + __shfl_xor(a8[i], 8, 64));
    if (lane < 8) {
        float4 w0 = make_float4(m8[0], m8[1], m8[2], m8[3]);
        float4 w1 = make_float4(m8[4], m8[5], m8[6], m8[7]);
        *(float4*)&hout[(size_t)n * 64 + 8 * lane] = w0;
        *(float4*)&hout[(size_t)n * 64 + 8 * lane + 4] = w1;
    }

    if (doGate) {
        float val = 0.f;
        if (lane < 8) {
#pragma unroll
            for (int i = 0; i < 8; i++) val += m8[i] * wg[8 * lane + i];
        }
        val += __shfl_xor(val, 1, 64);
        val += __shfl_xor(val, 2, 64);
        val += __shfl_xor(val, 4, 64);
        if (lane == 0) gatev[n] = val + bg[0];
    }
}

// ---------------------------------------------------------------------------
// Pooling: per-block-reduced max (256 atomics total), then fused
// exp+accumulate (unnormalized).
// ---------------------------------------------------------------------------
__global__ void pool_max_kernel(const float* __restrict__ gatev, const int* __restrict__ gids,
                                unsigned int* __restrict__ gmEnc) {
    int g = blockIdx.x / PB, b = blockIdx.x % PB;
    __shared__ int sb[2];
    int t = threadIdx.x;
    if (t == 0) { sb[0] = lower_bound_g(gids, g, NN); sb[1] = lower_bound_g(gids, g + 1, NN); }
    __syncthreads();
    int lo = sb[0], len = sb[1] - lo;
    int s = lo + (int)((long long)b * len / PB);
    int e = lo + (int)((long long)(b + 1) * len / PB);
    float m = -3.4e38f;
    for (int n = s + t; n < e; n += 256) m = fmaxf(m, gatev[n]);
    __shared__ float red[4];
    int w = t >> 6, lane = t & 63;
    for (int off = 32; off; off >>= 1) m = fmaxf(m, __shfl_down(m, off, 64));
    if (lane == 0) red[w] = m;
    __syncthreads();
    if (t == 0) {
        m = fmaxf(fmaxf(red[0], red[1]), fmaxf(red[2], red[3]));
        atomicMax(&gmEnc[g], encf(m));
    }
}

__global__ void pool_expacc_kernel(const float* __restrict__ h2, const float* __restrict__ gatev,
                                   const int* __restrict__ gids,
                                   const unsigned int* __restrict__ gmEnc,
                                   float* __restrict__ out_a, float* __restrict__ gsum,
                                   float* __restrict__ hgacc) {
    int g = blockIdx.x / PB, b = blockIdx.x % PB;
    __shared__ int sb[2];
    int t = threadIdx.x;
    if (t == 0) { sb[0] = lower_bound_g(gids, g, NN); sb[1] = lower_bound_g(gids, g + 1, NN); }
    __syncthreads();
    int lo = sb[0], len = sb[1] - lo;
    int s = lo + (int)((long long)b * len / PB);
    int e = lo + (int)((long long)(b + 1) * len / PB);
    float m = decf(gmEnc[g]);
    int sub = t >> 6, c = t & 63;
    float acc = 0.f, esum = 0.f;
    for (int n = s + sub; n < e; n += 4) {
        float ev = __expf(gatev[n] - m);
        if (c == 0) out_a[n] = ev;
        esum += ev;
        acc += ev * h2[(size_t)n * 64 + c];
    }
    __shared__ float sh[4][64];
    sh[sub][c] = acc;
    __syncthreads();
    if (sub == 0) atomicAdd(&hgacc[g * 64 + c], sh[0][c] + sh[1][c] + sh[2][c] + sh[3][c]);
    if (c == 0) atomicAdd(&gsum[g], esum);  // 4 partials per block
}

// ---------------------------------------------------------------------------
// Fused epilogue: block 0 = classifier (hg scale + copy + MLP + sigmoid);
// blocks 1..N = scale out_a by 1/gsum.
// ---------------------------------------------------------------------------
__global__ __launch_bounds__(512) void epilogue_kernel(
        const float* __restrict__ hgacc, const float* __restrict__ gsum,
        const float* __restrict__ Wc1, const float* __restrict__ bc1,
        const float* __restrict__ Wc2, const float* __restrict__ bc2,
        const int* __restrict__ gids, float* __restrict__ out,
        float* __restrict__ out_a, float* __restrict__ out_hg) {
    int t = threadIdx.x;  // [0,512)
    if (blockIdx.x != 0) {
        int n = (blockIdx.x - 1) * 512 + t;
        if (n < NN) {
            float sv = gsum[gids[n]];
            out_a[n] *= (sv > 0.f) ? 1.f / sv : 0.f;
        }
        return;
    }
    __shared__ float hgs[GG * 64];
    __shared__ float a2s[GG * 64];
    int g = t >> 6, c = t & 63;
    float sv = gsum[g];
    float inv = (sv > 0.f) ? 1.f / sv : 0.f;
    float hval = hgacc[t] * inv;
    hgs[t] = hval;
    out_hg[t] = hval;
    __syncthreads();
    float acc = bc1[c];
    for (int k = 0; k < 64; k++) acc += hgs[g * 64 + k] * Wc1[k * 64 + c];
    a2s[g * 64 + c] = acc;
    __syncthreads();
    if (t < GG * 2) {
        int gg = t >> 1, j = t & 1;
        float a3 = bc2[j];
        for (int k = 0; k < 64; k++) a3 += a2s[gg * 64 + k] * Wc2[k * 2 + j];
        out[t] = 1.f / (1.f + expf(-a3));
    }
}

// ---------------------------------------------------------------------------
extern "C" void kernel_launch(void* const* d_in, const int* in_sizes, int n_in,
                              void* d_out, int out_size, void* d_ws, size_t ws_size,
                              hipStream_t stream) {
    const float* h_n  = (const float*)d_in[0];
    const int*   src  = (const int*)d_in[1];
    const int*   dst  = (const int*)d_in[2];
    const int*   gids = (const int*)d_in[3];
    const float* Wfc1 = (const float*)d_in[4];
    const float* al1  = (const float*)d_in[5];
    const float* ar1  = (const float*)d_in[6];
    const float* Wfc2 = (const float*)d_in[7];
    const float* al2  = (const float*)d_in[8];
    const float* ar2  = (const float*)d_in[9];
    const float* wg   = (const float*)d_in[10];
    const float* bg   = (const float*)d_in[11];
    const float* Wc1  = (const float*)d_in[12];
    const float* bc1  = (const float*)d_in[13];
    const float* Wc2  = (const float*)d_in[14];
    const float* bc2  = (const float*)d_in[15];
    float* out = (float*)d_out;

    // workspace layout
    float* ws     = (float*)d_ws;
    unsigned int* featb = (unsigned int*)ws;     // N*64 uints (bf16x2 packed)
    float* el     = ws + (size_t)NN * 64;        // N*2
    float* er     = el + NN * 2;                 // N*2
    float* hbuf   = er + NN * 2;                 // N*64
    float* gatev  = hbuf + (size_t)NN * 64;      // N
    // --- zero-init region (one memset): gmEnc, gsum, hgacc, cnt ---
    unsigned int* gmEnc = (unsigned int*)(gatev + NN);  // 8
    float* gsum   = (float*)(gmEnc + GG);        // 8
    float* hgacc  = gsum + GG;                   // 512
    int*   cnt    = (int*)(hgacc + GG * 64);     // N
    // --- end zero-init region ---
    unsigned short* esrc = (unsigned short*)(cnt + NN);  // N*CAP uint16

    size_t zero_bytes = (GG + GG + GG * 64 + NN) * 4;
    hipMemsetAsync(gmEnc, 0, zero_bytes, stream);

    // ---- edge-bucket scatter (standalone: full occupancy, no LDS) ----
    scatter_kernel<<<(EE + 255) / 256, 256, 0, stream>>>(src, dst, cnt, esrc, EE);

    // ---- GAT layer 1 ----
    fc_attn_kernel<<<(NN + TM - 1) / TM, 256, 0, stream>>>(h_n, Wfc1, al1, ar1,
                                                           featb, el, er, 128, NN);
    gat_agg_kernel<<<(NN + 3) / 4, 256, 0, stream>>>(featb, el, er, cnt, esrc, hbuf,
                                                     wg, bg, gatev, 0);

    // ---- GAT layer 2 (gate fused into epilogue) ----
    fc_attn_kernel<<<(NN + TM - 1) / TM, 256, 0, stream>>>(hbuf, Wfc2, al2, ar2,
                                                           featb, el, er, 64, NN);
    gat_agg_kernel<<<(NN + 3) / 4, 256, 0, stream>>>(featb, el, er, cnt, esrc, hbuf,
                                                     wg, bg, gatev, 1);

    // ---- global attention pooling ----
    pool_max_kernel<<<GG * PB, 256, 0, stream>>>(gatev, gids, gmEnc);
    pool_expacc_kernel<<<GG * PB, 256, 0, stream>>>(hbuf, gatev, gids, gmEnc,
                                                    out + GG * 2, gsum, hgacc);

    // ---- fused epilogue: classifier (block 0) + out_a scaling (rest) ----
    int nb = 1 + (NN + 511) / 512;
    epilogue_kernel<<<nb, 512, 0, stream>>>(hgacc, gsum, Wc1, bc1, Wc2, bc2, gids,
                                            out, out + GG * 2, out + GG * 2 + NN);
}

// Round 17
// 277.215 us; speedup vs baseline: 1.0323x; 1.0323x over previous
//
#include <hip/hip_runtime.h>
#include <hip/hip_bf16.h>

#define NN 50000
#define EE 500000
#define GG 8
#define INDIM 128
#define HID 64
#define NH 2
#define PB 32          // slice-blocks per graph in pooling stages
#define TM 32          // nodes per fc block (R11 proven; TM64 regressed R12)
#define KC 32          // k-chunk staged in LDS
#define CAP 64         // edge bucket capacity per node (max observed deg ~30)
#define NB_SC ((EE + 255) / 256)   // scatter blocks in fused kernel

// bf16 helpers (manual RTNE pack / bit-shift unpack)
__device__ inline unsigned short f2bf(float f) {
    unsigned int u = __float_as_uint(f);
    unsigned int r = (u + 0x7FFFu + ((u >> 16) & 1u)) >> 16;
    return (unsigned short)r;
}
__device__ inline unsigned int pack_bf16x2(float lo, float hi) {
    return (unsigned int)f2bf(lo) | ((unsigned int)f2bf(hi) << 16);
}
// order-preserving float<->uint encoding for atomicMax (0 < enc(any float))
__device__ inline unsigned int encf(float f) {
    unsigned int u = __float_as_uint(f);
    return (u & 0x80000000u) ? ~u : (u | 0x80000000u);
}
__device__ inline float decf(unsigned int e) {
    unsigned int u = (e & 0x80000000u) ? (e & 0x7FFFFFFFu) : ~e;
    return __uint_as_float(u);
}
__device__ inline int lower_bound_g(const int* __restrict__ gids, int target, int N) {
    int lo = 0, hi = N;
    while (lo < hi) { int mid = (lo + hi) >> 1; if (gids[mid] < target) lo = mid + 1; else hi = mid; }
    return lo;
}

// ---------------------------------------------------------------------------
// fc body (R11 TM=32 form): 256 threads -> 32 nodes x 128 cols, 4x4/thread.
// ---------------------------------------------------------------------------
__device__ __forceinline__ void fc_attn_body(
        int bid, const float* __restrict__ X, const float* __restrict__ W,
        const float* __restrict__ al, const float* __restrict__ ar,
        unsigned int* __restrict__ featb, float* __restrict__ el,
        float* __restrict__ er, int K, int N) {
    int t = threadIdx.x;
    int tx = t & 31, ty = t >> 5;
    int n0 = bid * TM;
    __shared__ float xT[KC][TM + 4];
    __shared__ float Wsh[KC][128];
    float acc[4][4] = {{0.f}};

    for (int kc = 0; kc < K; kc += KC) {
        {
            int r = t >> 3;
            int c4 = (t & 7) * 4;
            int n = n0 + r;
            float4 v = make_float4(0.f, 0.f, 0.f, 0.f);
            if (n < N) v = *(const float4*)&X[(size_t)n * K + kc + c4];
            xT[c4 + 0][r] = v.x;
            xT[c4 + 1][r] = v.y;
            xT[c4 + 2][r] = v.z;
            xT[c4 + 3][r] = v.w;
        }
        {
            const float4* Wg = (const float4*)&W[(size_t)kc * 128];
            float4* Ws4 = (float4*)&Wsh[0][0];
#pragma unroll
            for (int i = 0; i < 4; i++) Ws4[t + 256 * i] = Wg[t + 256 * i];
        }
        __syncthreads();
#pragma unroll
        for (int k = 0; k < KC; k++) {
            float4 xv = *(float4*)&xT[k][ty * 4];
            float4 wv = *(float4*)&Wsh[k][tx * 4];
            float xs[4] = {xv.x, xv.y, xv.z, xv.w};
            float wsv[4] = {wv.x, wv.y, wv.z, wv.w};
#pragma unroll
            for (int i = 0; i < 4; i++)
#pragma unroll
                for (int j = 0; j < 4; j++) acc[i][j] += xs[i] * wsv[j];
        }
        __syncthreads();
    }

    int head = tx >> 4;
    float alv[4], arv[4];
#pragma unroll
    for (int j = 0; j < 4; j++) {
        alv[j] = al[tx * 4 + j];
        arv[j] = ar[tx * 4 + j];
    }
#pragma unroll
    for (int i = 0; i < 4; i++) {
        int r = n0 + ty * 4 + i;
        if (r < N) {
            uint2 pk;
            pk.x = pack_bf16x2(acc[i][0], acc[i][1]);
            pk.y = pack_bf16x2(acc[i][2], acc[i][3]);
            *(uint2*)&featb[(size_t)r * 64 + tx * 2] = pk;
            float pl = 0.f, pr = 0.f;
#pragma unroll
            for (int j = 0; j < 4; j++) {
                pl += acc[i][j] * alv[j];
                pr += acc[i][j] * arv[j];
            }
            for (int off = 8; off; off >>= 1) {
                pl += __shfl_xor(pl, off, 64);
                pr += __shfl_xor(pr, off, 64);
            }
            if ((tx & 15) == 0) {
                el[r * 2 + head] = pl;
                er[r * 2 + head] = pr;
            }
        }
    }
}

// ---------------------------------------------------------------------------
// Fused: blocks [0, NB_SC) bucket-scatter (uint16 payload); rest fc layer 1.
// (R16 measured: splitting these regresses by ~5 us — keep fused.)
// ---------------------------------------------------------------------------
__global__ __launch_bounds__(256) void build_fc1_kernel(
        const int* __restrict__ src, const int* __restrict__ dst,
        int* __restrict__ cnt, unsigned short* __restrict__ esrc,
        const float* __restrict__ X, const float* __restrict__ W,
        const float* __restrict__ al, const float* __restrict__ ar,
        unsigned int* __restrict__ featb, float* __restrict__ el,
        float* __restrict__ er) {
    if (blockIdx.x < NB_SC) {
        int e = blockIdx.x * 256 + threadIdx.x;
        if (e < EE) {
            int d = dst[e];
            int pos = atomicAdd(&cnt[d], 1);
            if (pos < CAP) esrc[(size_t)d * CAP + pos] = (unsigned short)src[e];
        }
        return;
    }
    fc_attn_body(blockIdx.x - NB_SC, X, W, al, ar, featb, el, er, 128, NN);
}

__global__ __launch_bounds__(256) void fc_attn_kernel(
        const float* __restrict__ X, const float* __restrict__ W,
        const float* __restrict__ al, const float* __restrict__ ar,
        unsigned int* __restrict__ featb, float* __restrict__ el,
        float* __restrict__ er, int K, int N) {
    fc_attn_body(blockIdx.x, X, W, al, ar, featb, el, er, K, N);
}

// ---------------------------------------------------------------------------
// GAT edge softmax + aggregation + relu + head-mean: ONE WAVE PER NODE,
// FOUR EDGES PER ITERATION (R11 inline-shuffle gather — proven optimal).
// Edge-softmax computed WITHOUT max subtraction (mathematically identical,
// scores O(+-12) so fp32 exp is safe) — drops 6 dependent shuffles/node.
// ---------------------------------------------------------------------------
__global__ void gat_agg_kernel(const unsigned int* __restrict__ featb,
                               const float* __restrict__ el,
                               const float* __restrict__ er, const int* __restrict__ cnt,
                               const unsigned short* __restrict__ esrc,
                               float* __restrict__ hout,
                               const float* __restrict__ wg, const float* __restrict__ bg,
                               float* __restrict__ gatev, int doGate) {
    int wid = threadIdx.x >> 6;
    int lane = threadIdx.x & 63;
    int n = blockIdx.x * 4 + wid;
    if (n >= NN) return;
    int deg = cnt[n];
    deg = deg > CAP ? CAP : deg;
    int q = lane >> 4;     // which edge of a quad
    int l4 = lane & 15;    // covers uints 4*l4..4*l4+3 = cols 8*l4..8*l4+7
    float a8[8];
#pragma unroll
    for (int i = 0; i < 8; i++) a8[i] = 0.f;

    if (deg > 0) {
        float2 erv = ((const float2*)er)[n];
        bool v = lane < deg;
        int s = (int)esrc[(size_t)n * CAP + (v ? lane : 0)];
        float2 elv = ((const float2*)el)[s];
        float e0 = elv.x + erv.x; e0 = e0 > 0.f ? e0 : 0.2f * e0;
        float e1 = elv.y + erv.y; e1 = e1 > 0.f ? e1 : 0.2f * e1;
        float x0 = v ? __expf(e0) : 0.f;
        float x1 = v ? __expf(e1) : 0.f;
        float d0 = x0, d1 = x1;
        for (int off = 32; off; off >>= 1) {
            d0 += __shfl_xor(d0, off, 64);
            d1 += __shfl_xor(d1, off, 64);
        }
        float a0 = x0 / d0, a1 = x1 / d1;
        int headHi = (l4 >= 8);
        for (int e = 0; e < deg; e += 4) {
            int myE = e + q;
            bool ve = myE < deg;
            int pick = ve ? myE : e;
            int se = __shfl(s, pick, 64);
            float av0 = __shfl(a0, pick, 64);
            float av1 = __shfl(a1, pick, 64);
            float a = headHi ? av1 : av0;
            if (!ve) a = 0.f;
            uint4 fv = *(const uint4*)&featb[(size_t)se * 64 + l4 * 4];
            a8[0] += a * __uint_as_float(fv.x << 16);
            a8[1] += a * __uint_as_float(fv.x & 0xFFFF0000u);
            a8[2] += a * __uint_as_float(fv.y << 16);
            a8[3] += a * __uint_as_float(fv.y & 0xFFFF0000u);
            a8[4] += a * __uint_as_float(fv.z << 16);
            a8[5] += a * __uint_as_float(fv.z & 0xFFFF0000u);
            a8[6] += a * __uint_as_float(fv.w << 16);
            a8[7] += a * __uint_as_float(fv.w & 0xFFFF0000u);
        }
    }

    // combine quads (same cols, disjoint edge subsets), then relu
#pragma unroll
    for (int i = 0; i < 8; i++) {
        a8[i] += __shfl_xor(a8[i], 16, 64);
        a8[i] += __shfl_xor(a8[i], 32, 64);
        a8[i] = fmaxf(a8[i], 0.f);
    }
    // head mean: lane l4 pairs with l4^8 (head0 cols 8*l4.. <-> head1 same offset)
    float m8[8];
#pragma unroll
    for (int i = 0; i < 8; i++) m8[i] = 0.5f * (a8[i] + __shfl_xor(a8[i], 8, 64));
    if (lane < 8) {
        float4 w0 = make_float4(m8[0], m8[1], m8[2], m8[3]);
        float4 w1 = make_float4(m8[4], m8[5], m8[6], m8[7]);
        *(float4*)&hout[(size_t)n * 64 + 8 * lane] = w0;
        *(float4*)&hout[(size_t)n * 64 + 8 * lane + 4] = w1;
    }

    if (doGate) {
        float val = 0.f;
        if (lane < 8) {
#pragma unroll
            for (int i = 0; i < 8; i++) val += m8[i] * wg[8 * lane + i];
        }
        val += __shfl_xor(val, 1, 64);
        val += __shfl_xor(val, 2, 64);
        val += __shfl_xor(val, 4, 64);
        if (lane == 0) gatev[n] = val + bg[0];
    }
}

// ---------------------------------------------------------------------------
// Pooling: per-block-reduced max (256 atomics total), then fused
// exp+accumulate (unnormalized).
// ---------------------------------------------------------------------------
__global__ void pool_max_kernel(const float* __restrict__ gatev, const int* __restrict__ gids,
                                unsigned int* __restrict__ gmEnc) {
    int g = blockIdx.x / PB, b = blockIdx.x % PB;
    __shared__ int sb[2];
    int t = threadIdx.x;
    if (t == 0) { sb[0] = lower_bound_g(gids, g, NN); sb[1] = lower_bound_g(gids, g + 1, NN); }
    __syncthreads();
    int lo = sb[0], len = sb[1] - lo;
    int s = lo + (int)((long long)b * len / PB);
    int e = lo + (int)((long long)(b + 1) * len / PB);
    float m = -3.4e38f;
    for (int n = s + t; n < e; n += 256) m = fmaxf(m, gatev[n]);
    __shared__ float red[4];
    int w = t >> 6, lane = t & 63;
    for (int off = 32; off; off >>= 1) m = fmaxf(m, __shfl_down(m, off, 64));
    if (lane == 0) red[w] = m;
    __syncthreads();
    if (t == 0) {
        m = fmaxf(fmaxf(red[0], red[1]), fmaxf(red[2], red[3]));
        atomicMax(&gmEnc[g], encf(m));
    }
}

__global__ void pool_expacc_kernel(const float* __restrict__ h2, const float* __restrict__ gatev,
                                   const int* __restrict__ gids,
                                   const unsigned int* __restrict__ gmEnc,
                                   float* __restrict__ out_a, float* __restrict__ gsum,
                                   float* __restrict__ hgacc) {
    int g = blockIdx.x / PB, b = blockIdx.x % PB;
    __shared__ int sb[2];
    int t = threadIdx.x;
    if (t == 0) { sb[0] = lower_bound_g(gids, g, NN); sb[1] = lower_bound_g(gids, g + 1, NN); }
    __syncthreads();
    int lo = sb[0], len = sb[1] - lo;
    int s = lo + (int)((long long)b * len / PB);
    int e = lo + (int)((long long)(b + 1) * len / PB);
    float m = decf(gmEnc[g]);
    int sub = t >> 6, c = t & 63;
    float acc = 0.f, esum = 0.f;
    for (int n = s + sub; n < e; n += 4) {
        float ev = __expf(gatev[n] - m);
        if (c == 0) out_a[n] = ev;
        esum += ev;
        acc += ev * h2[(size_t)n * 64 + c];
    }
    __shared__ float sh[4][64];
    sh[sub][c] = acc;
    __syncthreads();
    if (sub == 0) atomicAdd(&hgacc[g * 64 + c], sh[0][c] + sh[1][c] + sh[2][c] + sh[3][c]);
    if (c == 0) atomicAdd(&gsum[g], esum);  // 4 partials per block
}

// ---------------------------------------------------------------------------
// Fused epilogue: block 0 = classifier (hg scale + copy + MLP + sigmoid);
// blocks 1..N = scale out_a by 1/gsum.
// ---------------------------------------------------------------------------
__global__ __launch_bounds__(512) void epilogue_kernel(
        const float* __restrict__ hgacc, const float* __restrict__ gsum,
        const float* __restrict__ Wc1, const float* __restrict__ bc1,
        const float* __restrict__ Wc2, const float* __restrict__ bc2,
        const int* __restrict__ gids, float* __restrict__ out,
        float* __restrict__ out_a, float* __restrict__ out_hg) {
    int t = threadIdx.x;  // [0,512)
    if (blockIdx.x != 0) {
        int n = (blockIdx.x - 1) * 512 + t;
        if (n < NN) {
            float sv = gsum[gids[n]];
            out_a[n] *= (sv > 0.f) ? 1.f / sv : 0.f;
        }
        return;
    }
    __shared__ float hgs[GG * 64];
    __shared__ float a2s[GG * 64];
    int g = t >> 6, c = t & 63;
    float sv = gsum[g];
    float inv = (sv > 0.f) ? 1.f / sv : 0.f;
    float hval = hgacc[t] * inv;
    hgs[t] = hval;
    out_hg[t] = hval;
    __syncthreads();
    float acc = bc1[c];
    for (int k = 0; k < 64; k++) acc += hgs[g * 64 + k] * Wc1[k * 64 + c];
    a2s[g * 64 + c] = acc;
    __syncthreads();
    if (t < GG * 2) {
        int gg = t >> 1, j = t & 1;
        float a3 = bc2[j];
        for (int k = 0; k < 64; k++) a3 += a2s[gg * 64 + k] * Wc2[k * 2 + j];
        out[t] = 1.f / (1.f + expf(-a3));
    }
}

// ---------------------------------------------------------------------------
extern "C" void kernel_launch(void* const* d_in, const int* in_sizes, int n_in,
                              void* d_out, int out_size, void* d_ws, size_t ws_size,
                              hipStream_t stream) {
    const float* h_n  = (const float*)d_in[0];
    const int*   src  = (const int*)d_in[1];
    const int*   dst  = (const int*)d_in[2];
    const int*   gids = (const int*)d_in[3];
    const float* Wfc1 = (const float*)d_in[4];
    const float* al1  = (const float*)d_in[5];
    const float* ar1  = (const float*)d_in[6];
    const float* Wfc2 = (const float*)d_in[7];
    const float* al2  = (const float*)d_in[8];
    const float* ar2  = (const float*)d_in[9];
    const float* wg   = (const float*)d_in[10];
    const float* bg   = (const float*)d_in[11];
    const float* Wc1  = (const float*)d_in[12];
    const float* bc1  = (const float*)d_in[13];
    const float* Wc2  = (const float*)d_in[14];
    const float* bc2  = (const float*)d_in[15];
    float* out = (float*)d_out;

    // workspace layout
    float* ws     = (float*)d_ws;
    unsigned int* featb = (unsigned int*)ws;     // N*64 uints (bf16x2 packed)
    float* el     = ws + (size_t)NN * 64;        // N*2
    float* er     = el + NN * 2;                 // N*2
    float* hbuf   = er + NN * 2;                 // N*64
    float* gatev  = hbuf + (size_t)NN * 64;      // N
    // --- zero-init region (one memset): gmEnc, gsum, hgacc, cnt ---
    unsigned int* gmEnc = (unsigned int*)(gatev + NN);  // 8
    float* gsum   = (float*)(gmEnc + GG);        // 8
    float* hgacc  = gsum + GG;                   // 512
    int*   cnt    = (int*)(hgacc + GG * 64);     // N
    // --- end zero-init region ---
    unsigned short* esrc = (unsigned short*)(cnt + NN);  // N*CAP uint16

    size_t zero_bytes = (GG + GG + GG * 64 + NN) * 4;
    hipMemsetAsync(gmEnc, 0, zero_bytes, stream);

    // ---- fused: edge-bucket scatter + GAT layer 1 fc (independent work) ----
    int nb1 = NB_SC + (NN + TM - 1) / TM;
    build_fc1_kernel<<<nb1, 256, 0, stream>>>(src, dst, cnt, esrc,
                                              h_n, Wfc1, al1, ar1, featb, el, er);
    gat_agg_kernel<<<(NN + 3) / 4, 256, 0, stream>>>(featb, el, er, cnt, esrc, hbuf,
                                                     wg, bg, gatev, 0);

    // ---- GAT layer 2 (gate fused into epilogue) ----
    fc_attn_kernel<<<(NN + TM - 1) / TM, 256, 0, stream>>>(hbuf, Wfc2, al2, ar2,
                                                           featb, el, er, 64, NN);
    gat_agg_kernel<<<(NN + 3) / 4, 256, 0, stream>>>(featb, el, er, cnt, esrc, hbuf,
                                                     wg, bg, gatev, 1);

    // ---- global attention pooling ----
    pool_max_kernel<<<GG * PB, 256, 0, stream>>>(gatev, gids, gmEnc);
    pool_expacc_kernel<<<GG * PB, 256, 0, stream>>>(hbuf, gatev, gids, gmEnc,
                                                    out + GG * 2, gsum, hgacc);

    // ---- fused epilogue: classifier (block 0) + out_a scaling (rest) ----
    int nb = 1 + (NN + 511) / 512;
    epilogue_kernel<<<nb, 512, 0, stream>>>(hgacc, gsum, Wc1, bc1, Wc2, bc2, gids,
                                            out, out + GG * 2, out + GG * 2 + NN);
}